// Round 1
// baseline (2879.874 us; speedup 1.0000x reference)
//
#include <hip/hip_runtime.h>
#include <cstdint>
#include <cstddef>

#define B_    4
#define N_TOK 1029
#define C_    1024
#define H_    16
#define DH_   64
#define L_    8
#define HID_  4096
#define M_TOK (B_*N_TOK)   // 4116
#define MP_   4224         // 33 * 128
#define KVT_  17           // ceil(1029/64)

typedef float f32x4 __attribute__((ext_vector_type(4)));
typedef short bf16x8 __attribute__((ext_vector_type(8)));

__device__ __forceinline__ uint16_t f2bf(float f) {
  uint32_t u = __float_as_uint(f);
  u += 0x7fffu + ((u >> 16) & 1u);   // round-to-nearest-even
  return (uint16_t)(u >> 16);
}

__device__ __forceinline__ void async_copy16(const uint16_t* src, uint16_t* lds_dst) {
  __builtin_amdgcn_global_load_lds(
      (const __attribute__((address_space(1))) void*)src,
      (__attribute__((address_space(3))) void*)lds_dst, 16, 0, 0);
}

// byte offset into a [rows][64] bf16 LDS tile with XOR swizzle (slot ^= row&7)
__device__ __forceinline__ int swz16(int row, int byte_in_row) {
  return row * 128 + (byte_in_row ^ ((row & 7) << 4));
}

// ---------------- weight conversion fp32 -> bf16 ----------------
__global__ __launch_bounds__(256)
void cvt_f32_bf16(const float* __restrict__ in, uint16_t* __restrict__ out, int n4) {
  int i = blockIdx.x * 256 + threadIdx.x;
  if (i < n4) {
    float4 v = reinterpret_cast<const float4*>(in)[i];
    uint64_t pk = (uint64_t)f2bf(v.x) | ((uint64_t)f2bf(v.y) << 16)
                | ((uint64_t)f2bf(v.z) << 32) | ((uint64_t)f2bf(v.w) << 48);
    reinterpret_cast<uint64_t*>(out)[i] = pk;
  }
}

// ---------------- LayerNorm (fp32 in, bf16 or fp32 out) ----------------
template<int OUTMODE>  // 0: bf16 out, 1: fp32 out
__global__ __launch_bounds__(256)
void ln_fwd(const float* __restrict__ x, const float* __restrict__ w,
            const float* __restrict__ b, void* __restrict__ outp) {
  const int row = blockIdx.x;
  const int tid = threadIdx.x;
  const float4 v = reinterpret_cast<const float4*>(x + (size_t)row * C_)[tid];
  float s  = v.x + v.y + v.z + v.w;
  float s2 = v.x*v.x + v.y*v.y + v.z*v.z + v.w*v.w;
  #pragma unroll
  for (int d = 1; d < 64; d <<= 1) {
    s  += __shfl_xor(s, d);
    s2 += __shfl_xor(s2, d);
  }
  __shared__ float red[8];
  const int wv = tid >> 6;
  if ((tid & 63) == 0) { red[wv] = s; red[wv + 4] = s2; }
  __syncthreads();
  s  = red[0] + red[1] + red[2] + red[3];
  s2 = red[4] + red[5] + red[6] + red[7];
  const float mu = s * (1.0f / C_);
  const float rs = rsqrtf(fmaxf(s2 * (1.0f / C_) - mu * mu, 0.0f) + 1e-6f);
  const float4 wv4 = reinterpret_cast<const float4*>(w)[tid];
  const float4 bv4 = reinterpret_cast<const float4*>(b)[tid];
  const float o0 = (v.x - mu) * rs * wv4.x + bv4.x;
  const float o1 = (v.y - mu) * rs * wv4.y + bv4.y;
  const float o2 = (v.z - mu) * rs * wv4.z + bv4.z;
  const float o3 = (v.w - mu) * rs * wv4.w + bv4.w;
  if (OUTMODE == 0) {
    uint64_t pk = (uint64_t)f2bf(o0) | ((uint64_t)f2bf(o1) << 16)
                | ((uint64_t)f2bf(o2) << 32) | ((uint64_t)f2bf(o3) << 48);
    reinterpret_cast<uint64_t*>((uint16_t*)outp + (size_t)row * C_)[tid] = pk;
  } else {
    float4 o; o.x = o0; o.y = o1; o.z = o2; o.w = o3;
    reinterpret_cast<float4*>((float*)outp + (size_t)row * C_)[tid] = o;
  }
}

// ---------------- GEMM: C[m,n] = sum_k A[m,k]*W[n,k] + bias[n] ----------------
// EPI 0: store bf16. EPI 1: GELU(exact) -> bf16. EPI 2: resid[m,n] += v (fp32, m<Mvalid)
template<int EPI>
__global__ __launch_bounds__(256, 2)
void gemm_bt(const uint16_t* __restrict__ A, const uint16_t* __restrict__ W,
             const float* __restrict__ bias, uint16_t* __restrict__ outb,
             float* __restrict__ resid, int Nn, int K, int Mvalid) {
  __shared__ uint16_t Asm_[128 * 64];
  __shared__ uint16_t Bsm_[128 * 64];
  const int tid = threadIdx.x;
  const int l = tid & 63, wid = tid >> 6;
  const int l15 = l & 15, l4 = l >> 4;
  const int wr = wid >> 1, wc = wid & 1;
  const int bm = blockIdx.x, bn = blockIdx.y;
  const int rsub = l >> 3;
  const int ssl = (l & 7) ^ rsub;

  const uint16_t* Ag = A + (size_t)bm * 128 * K;
  const uint16_t* Wg = W + (size_t)bn * 128 * K;

  f32x4 acc[4][4] = {};

  for (int kt = 0; kt < K; kt += 64) {
    #pragma unroll
    for (int cc = 0; cc < 4; ++cc) {
      const int c = wid * 4 + cc;
      const int row = c * 8 + rsub;
      const size_t goff = (size_t)row * K + kt + ssl * 8;
      async_copy16(Ag + goff, Asm_ + c * 512);
      async_copy16(Wg + goff, Bsm_ + c * 512);
    }
    __syncthreads();
    #pragma unroll
    for (int kk = 0; kk < 2; ++kk) {
      bf16x8 af[4], bfr[4];
      #pragma unroll
      for (int i = 0; i < 4; ++i) {
        const int r = wr * 64 + i * 16 + l15;
        af[i] = *(const bf16x8*)((const char*)Asm_ + swz16(r, kk * 64 + l4 * 16));
      }
      #pragma unroll
      for (int j = 0; j < 4; ++j) {
        const int r = wc * 64 + j * 16 + l15;
        bfr[j] = *(const bf16x8*)((const char*)Bsm_ + swz16(r, kk * 64 + l4 * 16));
      }
      #pragma unroll
      for (int i = 0; i < 4; ++i)
        #pragma unroll
        for (int j = 0; j < 4; ++j)
          acc[i][j] = __builtin_amdgcn_mfma_f32_16x16x32_bf16(af[i], bfr[j], acc[i][j], 0, 0, 0);
    }
    __syncthreads();
  }

  #pragma unroll
  for (int j = 0; j < 4; ++j) {
    const int col = bn * 128 + wc * 64 + j * 16 + l15;
    const float bv = bias[col];
    #pragma unroll
    for (int i = 0; i < 4; ++i) {
      const int mbase = bm * 128 + wr * 64 + i * 16 + l4 * 4;
      #pragma unroll
      for (int r = 0; r < 4; ++r) {
        const int m = mbase + r;
        const float v = acc[i][j][r] + bv;
        if (EPI == 0) {
          outb[(size_t)m * Nn + col] = f2bf(v);
        } else if (EPI == 1) {
          const float g = 0.5f * v * (1.0f + erff(v * 0.70710678118f));
          outb[(size_t)m * Nn + col] = f2bf(g);
        } else {
          if (m < Mvalid) resid[(size_t)m * Nn + col] += v;
        }
      }
    }
  }
}

// ---------------- Flash attention: qkv [MP_,3072] bf16 -> o [MP_,1024] bf16 ----------------
__global__ __launch_bounds__(256, 2)
void attn_fwd(const uint16_t* __restrict__ qkv, uint16_t* __restrict__ ob) {
  __shared__ uint16_t Ksm_[64 * 64];       // [key][d], source-swizzled
  __shared__ uint16_t Vsm_[64 * 64];       // transposed: [d][key], XOR-swizzled
  __shared__ uint16_t Psm_[4][16 * 72];    // per wave: [16 q][64 key + pad]

  const int tid = threadIdx.x;
  const int l = tid & 63, w = tid >> 6;
  const int l15 = l & 15, l4 = l >> 4;
  const int bh = blockIdx.x;
  const int b = bh >> 4, h = bh & 15;
  const int qt = blockIdx.y;
  const int rsub = l >> 3;
  const int ssl = (l & 7) ^ rsub;

  // Q fragments held in registers for all KV tiles
  bf16x8 qf[2];
  {
    const int qrow = qt * 64 + w * 16 + l15;
    const uint16_t* qbase = qkv + (size_t)(b * N_TOK + qrow) * 3072 + h * 64;
    qf[0] = *(const bf16x8*)(qbase + l4 * 8);
    qf[1] = *(const bf16x8*)(qbase + 32 + l4 * 8);
  }

  float mrow[4], lrow[4];
  f32x4 oacc[4] = {};
  #pragma unroll
  for (int r = 0; r < 4; ++r) { mrow[r] = -1e30f; lrow[r] = 0.0f; }

  for (int kt = 0; kt < KVT_; ++kt) {
    const int key0 = kt * 64;
    __syncthreads();
    // stage K (swizzled source -> linear LDS)
    #pragma unroll
    for (int cc = 0; cc < 2; ++cc) {
      const int c = w * 2 + cc;
      const int krow = c * 8 + rsub;
      const uint16_t* src = qkv + (size_t)(b * N_TOK + key0 + krow) * 3072 + 1024 + h * 64 + ssl * 8;
      async_copy16(src, Ksm_ + c * 512);
    }
    // stage V transposed (reg staging, swizzled scatter writes)
    {
      const int a  = tid & 7;    // d-block
      const int kb = tid >> 3;   // 0..31
      #pragma unroll
      for (int it = 0; it < 2; ++it) {
        const int key = kb + it * 32;
        const bf16x8 vv = *(const bf16x8*)(qkv + (size_t)(b * N_TOK + key0 + key) * 3072 + 2048 + h * 64 + a * 8);
        #pragma unroll
        for (int j = 0; j < 8; ++j) {
          const int d = a * 8 + j;
          const int byteoff = d * 128 + ((key * 2) ^ ((((d & 7) ^ ((d >> 3) & 7))) << 4));
          *(uint16_t*)((char*)Vsm_ + byteoff) = (uint16_t)vv[j];
        }
      }
    }
    __syncthreads();

    // S = Q K^T
    f32x4 s[4] = {};
    #pragma unroll
    for (int kk = 0; kk < 2; ++kk) {
      #pragma unroll
      for (int kf = 0; kf < 4; ++kf) {
        const int r = kf * 16 + l15;
        const bf16x8 kfrag = *(const bf16x8*)((const char*)Ksm_ + swz16(r, kk * 64 + l4 * 16));
        s[kf] = __builtin_amdgcn_mfma_f32_16x16x32_bf16(qf[kk], kfrag, s[kf], 0, 0, 0);
      }
    }
    // scale + key mask + row max
    float mnew[4] = {-1e30f, -1e30f, -1e30f, -1e30f};
    #pragma unroll
    for (int kf = 0; kf < 4; ++kf) {
      const bool valid = (key0 + kf * 16 + l15) < N_TOK;
      #pragma unroll
      for (int r = 0; r < 4; ++r) {
        const float sv = valid ? s[kf][r] * 0.125f : -1e30f;
        s[kf][r] = sv;
        mnew[r] = fmaxf(mnew[r], sv);
      }
    }
    #pragma unroll
    for (int r = 0; r < 4; ++r) {
      #pragma unroll
      for (int dlt = 1; dlt < 16; dlt <<= 1)
        mnew[r] = fmaxf(mnew[r], __shfl_xor(mnew[r], dlt));
    }
    // online rescale
    #pragma unroll
    for (int r = 0; r < 4; ++r) {
      const float mi = fmaxf(mrow[r], mnew[r]);
      const float sc = __expf(mrow[r] - mi);
      mrow[r] = mi;
      lrow[r] *= sc;
      #pragma unroll
      for (int d = 0; d < 4; ++d) oacc[d][r] *= sc;
    }
    // P = exp(S - m), write to per-wave LDS; accumulate row sums
    float psum[4] = {0.f, 0.f, 0.f, 0.f};
    #pragma unroll
    for (int kf = 0; kf < 4; ++kf) {
      #pragma unroll
      for (int r = 0; r < 4; ++r) {
        const float p = __expf(s[kf][r] - mrow[r]);
        psum[r] += p;
        Psm_[w][(l4 * 4 + r) * 72 + kf * 16 + l15] = f2bf(p);
      }
    }
    #pragma unroll
    for (int r = 0; r < 4; ++r) {
      #pragma unroll
      for (int dlt = 1; dlt < 16; dlt <<= 1)
        psum[r] += __shfl_xor(psum[r], dlt);
      lrow[r] += psum[r];
    }
    // O += P V
    #pragma unroll
    for (int kk = 0; kk < 2; ++kk) {
      const bf16x8 pf = *(const bf16x8*)(&Psm_[w][l15 * 72 + kk * 32 + l4 * 8]);
      #pragma unroll
      for (int df = 0; df < 4; ++df) {
        const int d = df * 16 + l15;
        const int byteoff = d * 128 + ((kk * 64 + l4 * 16) ^ ((((d & 7) ^ ((d >> 3) & 7))) << 4));
        const bf16x8 vf = *(const bf16x8*)((const char*)Vsm_ + byteoff);
        oacc[df] = __builtin_amdgcn_mfma_f32_16x16x32_bf16(pf, vf, oacc[df], 0, 0, 0);
      }
    }
  }
  // normalize + store
  #pragma unroll
  for (int r = 0; r < 4; ++r) {
    const int q = qt * 64 + w * 16 + l4 * 4 + r;
    if (q < N_TOK) {
      const float inv = 1.0f / lrow[r];
      #pragma unroll
      for (int df = 0; df < 4; ++df)
        ob[(size_t)(b * N_TOK + q) * 1024 + h * 64 + df * 16 + l15] = f2bf(oacc[df][r] * inv);
    }
  }
}

extern "C" void kernel_launch(void* const* d_in, const int* in_sizes, int n_in,
                              void* d_out, int out_size, void* d_ws, size_t ws_size,
                              hipStream_t stream) {
  const float* x_in   = (const float*)d_in[0];
  const float* ln1_w  = (const float*)d_in[1];
  const float* ln1_b  = (const float*)d_in[2];
  const float* qkv_w  = (const float*)d_in[3];
  const float* qkv_b  = (const float*)d_in[4];
  const float* proj_w = (const float*)d_in[5];
  const float* proj_b = (const float*)d_in[6];
  const float* ln2_w  = (const float*)d_in[7];
  const float* ln2_b  = (const float*)d_in[8];
  const float* fc1_w  = (const float*)d_in[9];
  const float* fc1_b  = (const float*)d_in[10];
  const float* fc2_w  = (const float*)d_in[11];
  const float* fc2_b  = (const float*)d_in[12];
  const float* norm_w = (const float*)d_in[13];
  const float* norm_b = (const float*)d_in[14];

  char* p = (char*)d_ws;
  float*    xbuf = (float*)p;     p += (size_t)MP_ * C_ * 4;
  uint16_t* hbuf = (uint16_t*)p;  p += (size_t)MP_ * C_ * 2;
  uint16_t* big  = (uint16_t*)p;  p += (size_t)MP_ * HID_ * 2;   // qkv / hid (shared lifetime)
  uint16_t* obuf = (uint16_t*)p;  p += (size_t)MP_ * C_ * 2;
  uint16_t* wq   = (uint16_t*)p;  p += (size_t)L_ * 3 * C_ * C_ * 2;
  uint16_t* wp   = (uint16_t*)p;  p += (size_t)L_ * C_ * C_ * 2;
  uint16_t* w1   = (uint16_t*)p;  p += (size_t)L_ * HID_ * C_ * 2;
  uint16_t* w2   = (uint16_t*)p;  p += (size_t)L_ * C_ * HID_ * 2;
  if ((size_t)(p - (char*)d_ws) > ws_size) return;  // fail loudly (output stays poisoned)

  hipMemcpyAsync(xbuf, x_in, (size_t)M_TOK * C_ * sizeof(float),
                 hipMemcpyDeviceToDevice, stream);

  auto cvt = [&](const float* src, uint16_t* dst, size_t n) {
    const int n4 = (int)(n / 4);
    cvt_f32_bf16<<<dim3((n4 + 255) / 256), dim3(256), 0, stream>>>(src, dst, n4);
  };
  cvt(qkv_w,  wq, (size_t)L_ * 3 * C_ * C_);
  cvt(proj_w, wp, (size_t)L_ * C_ * C_);
  cvt(fc1_w,  w1, (size_t)L_ * HID_ * C_);
  cvt(fc2_w,  w2, (size_t)L_ * C_ * HID_);

  for (int lyr = 0; lyr < L_; ++lyr) {
    ln_fwd<0><<<dim3(M_TOK), dim3(256), 0, stream>>>(
        xbuf, ln1_w + (size_t)lyr * C_, ln1_b + (size_t)lyr * C_, hbuf);
    gemm_bt<0><<<dim3(MP_ / 128, 3 * C_ / 128), dim3(256), 0, stream>>>(
        hbuf, wq + (size_t)lyr * 3 * C_ * C_, qkv_b + (size_t)lyr * 3 * C_,
        big, nullptr, 3 * C_, C_, M_TOK);
    attn_fwd<<<dim3(B_ * H_, KVT_), dim3(256), 0, stream>>>(big, obuf);
    gemm_bt<2><<<dim3(MP_ / 128, C_ / 128), dim3(256), 0, stream>>>(
        obuf, wp + (size_t)lyr * C_ * C_, proj_b + (size_t)lyr * C_,
        nullptr, xbuf, C_, C_, M_TOK);
    ln_fwd<0><<<dim3(M_TOK), dim3(256), 0, stream>>>(
        xbuf, ln2_w + (size_t)lyr * C_, ln2_b + (size_t)lyr * C_, hbuf);
    gemm_bt<1><<<dim3(MP_ / 128, HID_ / 128), dim3(256), 0, stream>>>(
        hbuf, w1 + (size_t)lyr * HID_ * C_, fc1_b + (size_t)lyr * HID_,
        big, nullptr, HID_, C_, M_TOK);
    gemm_bt<2><<<dim3(MP_ / 128, C_ / 128), dim3(256), 0, stream>>>(
        big, w2 + (size_t)lyr * C_ * HID_, fc2_b + (size_t)lyr * C_,
        nullptr, xbuf, C_, HID_, M_TOK);
  }
  ln_fwd<1><<<dim3(M_TOK), dim3(256), 0, stream>>>(xbuf, norm_w, norm_b, d_out);
}